// Round 3
// baseline (634.847 us; speedup 1.0000x reference)
//
#include <hip/hip_runtime.h>

// ---------------------------------------------------------------------------
// DeformableTransformer encoder layer, MI355X (gfx950).
// R2: gemm128 (m97-class: 128x128 tile, global_load_lds width=16, 16 MFMA per
// k-step per wave); deform_sample 32-bit saddr-form gather offsets.
// ---------------------------------------------------------------------------

#define BLTOK 52500   // B*L tokens
#define MP    52608   // BLTOK padded to multiple of 128
#define LSP   13125   // L (spatial length per batch)

using short8 = __attribute__((ext_vector_type(8))) short;
using f32x4  = __attribute__((ext_vector_type(4))) float;

__device__ __forceinline__ ushort f2b(float f) {
  union { float f; unsigned u; } x; x.f = f;
  unsigned r = (x.u + 0x7fffu + ((x.u >> 16) & 1u)) >> 16;
  return (ushort)r;
}
__device__ __forceinline__ float b2f(ushort h) {
  union { unsigned u; float f; } x; x.u = ((unsigned)h) << 16;
  return x.f;
}

#define GLDS16(gp, lp) __builtin_amdgcn_global_load_lds( \
    (const __attribute__((address_space(1))) void*)(gp), \
    (__attribute__((address_space(3))) void*)(lp), 16, 0, 0)

// ---------------- weight prep: transpose to N x K, convert bf16 -------------
// regions: Wv_t(256x256) Wcat_t(384x256, rows 320+ zero) Wout_t(256x256)
//          Wff1_t(1024x256) Wff2_t(256x1024) bcat(384 f32)
__global__ __launch_bounds__(256) void prep_weights(
    const float* __restrict__ Wv, const float* __restrict__ Woff,
    const float* __restrict__ Wattn, const float* __restrict__ Wout,
    const float* __restrict__ Wff1, const float* __restrict__ Wff2,
    const float* __restrict__ boff, const float* __restrict__ battn,
    ushort* __restrict__ wv_t, ushort* __restrict__ wcat_t,
    ushort* __restrict__ wout_t, ushort* __restrict__ wff1_t,
    ushort* __restrict__ wff2_t, float* __restrict__ bcat)
{
  int i = blockIdx.x * 256 + threadIdx.x;
  if (i < 65536) {
    int n = i >> 8, k = i & 255;
    wv_t[i] = f2b(Wv[k * 256 + n]);
    return;
  }
  int j = i - 65536;
  if (j < 98304) {                       // 384 rows
    int n = j >> 8, k = j & 255;
    float v = (n < 192) ? Woff[k * 192 + n]
            : (n < 288) ? Wattn[k * 96 + (n - 192)] : 0.f;
    wcat_t[j] = f2b(v);
    return;
  }
  j -= 98304;
  if (j < 65536) {
    int n = j >> 8, k = j & 255;
    wout_t[j] = f2b(Wout[k * 256 + n]);
    return;
  }
  j -= 65536;
  if (j < 262144) {
    int n = j >> 8, k = j & 255;
    wff1_t[j] = f2b(Wff1[k * 1024 + n]);
    return;
  }
  j -= 262144;
  if (j < 262144) {
    int n = j >> 10, k = j & 1023;
    wff2_t[j] = f2b(Wff2[k * 256 + n]);
    return;
  }
  j -= 262144;
  if (j < 384) bcat[j] = (j < 192) ? boff[j] : (j < 288) ? battn[j - 192] : 0.f;
}

// ---------------- activation prep: bf16 src and q=src+pos, zero pad rows ----
__global__ __launch_bounds__(256) void prep_act(
    const float* __restrict__ src, const float* __restrict__ pos,
    ushort* __restrict__ src_bf, ushort* __restrict__ q_bf)
{
  const size_t e = ((size_t)blockIdx.x * 256 + threadIdx.x) * 4;
  if (e >= (size_t)MP * 256) return;
  ushort4 sb, qb;
  if (e < (size_t)BLTOK * 256) {
    const float4 s = *(const float4*)(src + e);
    const float4 p = *(const float4*)(pos + e);
    sb.x = f2b(s.x); sb.y = f2b(s.y); sb.z = f2b(s.z); sb.w = f2b(s.w);
    qb.x = f2b(s.x + p.x); qb.y = f2b(s.y + p.y);
    qb.z = f2b(s.z + p.z); qb.w = f2b(s.w + p.w);
  } else {
    sb.x = sb.y = sb.z = sb.w = 0;
    qb.x = qb.y = qb.z = qb.w = 0;
  }
  *(ushort4*)(src_bf + e) = sb;
  *(ushort4*)(q_bf + e) = qb;
}

// ---------------- GEMM 128x128 (m97-class), C bf16 = A @ Bt^T + bias --------
// EPI: 0 = bias; 1 = + addf(f32); 2 = relu; 3 = + addb(bf16)
template <int EPI>
__global__ __launch_bounds__(256) void gemm128(
    const ushort* __restrict__ A, const ushort* __restrict__ Bt,
    const float* __restrict__ bias, const float* __restrict__ addf,
    const ushort* __restrict__ addb, ushort* __restrict__ C,
    int Mact, int Nact, int Nstr, int K)
{
  __shared__ __align__(16) ushort As[128 * 32];   // 8 KB, row-major [row][k]
  __shared__ __align__(16) ushort Bs[128 * 32];
  const int tid = threadIdx.x;
  const int wave = tid >> 6, lane = tid & 63;
  const int m0 = blockIdx.x * 128, n0 = blockIdx.y * 128;
  // staging: wave w covers tile rows [w*32, w*32+32); lane -> (row, 16B k-chunk)
  const int srow = lane >> 2, skc = (lane & 3) * 8;
  const ushort* Ag = A + (size_t)(m0 + wave * 32 + srow) * K + skc;
  const ushort* Bg = Bt + (size_t)(n0 + wave * 32 + srow) * K + skc;
  ushort* lA = &As[wave * 1024];       // wave-uniform LDS dest (lane x 16B)
  ushort* lB = &Bs[wave * 1024];
  const int quad = lane >> 4, l16 = lane & 15;
  const int wm = (wave & 1) * 64, wn = (wave >> 1) * 64;
  f32x4 acc[4][4] = {};
  for (int k0 = 0; k0 < K; k0 += 32) {
    GLDS16(Ag + k0, lA);
    GLDS16(Ag + k0 + 16 * K, lA + 512);
    GLDS16(Bg + k0, lB);
    GLDS16(Bg + k0 + 16 * K, lB + 512);
    __syncthreads();
    short8 af[4], bf[4];
#pragma unroll
    for (int i = 0; i < 4; i++)
      af[i] = *(const short8*)(&As[(wm + i * 16 + l16) * 32 + quad * 8]);
#pragma unroll
    for (int j = 0; j < 4; j++)
      bf[j] = *(const short8*)(&Bs[(wn + j * 16 + l16) * 32 + quad * 8]);
#pragma unroll
    for (int i = 0; i < 4; i++)
#pragma unroll
      for (int j = 0; j < 4; j++)
        acc[i][j] = __builtin_amdgcn_mfma_f32_16x16x32_bf16(af[i], bf[j],
                                                            acc[i][j], 0, 0, 0);
    __syncthreads();
  }
  // C/D: col = l16, row = quad*4 + reg   [m89/m91]
#pragma unroll
  for (int j = 0; j < 4; j++) {
    const int col = n0 + wn + j * 16 + l16;
    if (col >= Nact) continue;
    const float bb = bias[col];
#pragma unroll
    for (int i = 0; i < 4; i++) {
#pragma unroll
      for (int r = 0; r < 4; r++) {
        const int row = m0 + wm + i * 16 + quad * 4 + r;
        if (row < Mact) {
          const size_t idx = (size_t)row * Nstr + col;
          float v = acc[i][j][r] + bb;
          if (EPI == 1) v += addf[idx];
          if (EPI == 2) v = fmaxf(v, 0.f);
          if (EPI == 3) v += b2f(addb[idx]);
          C[idx] = f2b(v);
        }
      }
    }
  }
}

// ---------------- softmax over 12 attn logits per (token, head), in place ---
__global__ __launch_bounds__(256) void softmax12(ushort* __restrict__ offattn)
{
  const int t = blockIdx.x * 256 + threadIdx.x;
  if (t >= BLTOK * 8) return;
  const int r = t >> 3, h = t & 7;
  ushort* p = offattn + (size_t)r * 320 + 192 + h * 12;
  float v[12], mx = -1e30f;
#pragma unroll
  for (int i = 0; i < 12; i++) { v[i] = b2f(p[i]); mx = fmaxf(mx, v[i]); }
  float s = 0.f;
#pragma unroll
  for (int i = 0; i < 12; i++) { v[i] = expf(v[i] - mx); s += v[i]; }
  const float inv = 1.f / s;
#pragma unroll
  for (int i = 0; i < 12; i++) p[i] = f2b(v[i] * inv);
}

// ---------------- MS-deform-attn bilinear sampling core ---------------------
// 32 lanes/token: lane l -> head h=l>>2, 8 channels. 32-bit uint offsets off a
// uniform base -> saddr-form dwordx4 gathers. OOB via zeroed weights.
__global__ __launch_bounds__(256) void deform_sample(
    const ushort* __restrict__ value, const ushort* __restrict__ oa_all,
    const float* __restrict__ refp, ushort* __restrict__ outb)
{
  const int tid = threadIdx.x;
  const int tok = blockIdx.x * 8 + (tid >> 5);
  if (tok >= BLTOK) return;
  const int b = tok / LSP;
  const int l = tid & 31;
  const int h = l >> 2;
  const ushort* oa = oa_all + (uint)tok * 320u;
  const float* rp = refp + (uint)tok * 6u;
  const uint base = (uint)b * (LSP * 256u) + (uint)(l * 8);
  const int Wl[3] = {100, 50, 25};
  const int Stl[3] = {0, 10000, 12500};
  float acc[8] = {};
#pragma unroll
  for (int lid = 0; lid < 3; lid++) {
    const int W = Wl[lid], st = Stl[lid];   // square levels: H == W
    const float Wf = (float)W;
    const float rx = rp[lid * 2], ry = rp[lid * 2 + 1];
#pragma unroll
    for (int p = 0; p < 4; p++) {
      const uint oxy = *(const uint*)(oa + h * 24 + lid * 8 + p * 2);
      union { uint u; float f; } ux, uy;
      ux.u = oxy << 16;
      uy.u = oxy & 0xffff0000u;
      const float aw = b2f(oa[192 + h * 12 + lid * 4 + p]);
      const float x = (rx + ux.f / Wf) * Wf - 0.5f;
      const float y = (ry + uy.f / Wf) * Wf - 0.5f;
      const float x0f = floorf(x), y0f = floorf(y);
      const float wx1 = x - x0f, wy1 = y - y0f;
      const float wx0 = 1.f - wx1, wy0 = 1.f - wy1;
      const int ix0 = (int)x0f, iy0 = (int)y0f;
      const bool x0v = (ix0 >= 0) & (ix0 < W);
      const bool x1v = (ix0 + 1 >= 0) & (ix0 + 1 < W);
      const bool y0v = (iy0 >= 0) & (iy0 < W);
      const bool y1v = (iy0 + 1 >= 0) & (iy0 + 1 < W);
      const float ay0 = aw * wy0, ay1 = aw * wy1;
      float w00 = (x0v & y0v) ? ay0 * wx0 : 0.f;
      float w10 = (x1v & y0v) ? ay0 * wx1 : 0.f;
      float w01 = (x0v & y1v) ? ay1 * wx0 : 0.f;
      float w11 = (x1v & y1v) ? ay1 * wx1 : 0.f;
      const int ix0c = min(max(ix0, 0), W - 1);
      const int ix1c = min(max(ix0 + 1, 0), W - 1);
      const int iy0c = min(max(iy0, 0), W - 1);
      const int iy1c = min(max(iy0 + 1, 0), W - 1);
      const uint r00 = (uint)(st + iy0c * W + ix0c) * 256u;
      const uint r10 = (uint)(st + iy0c * W + ix1c) * 256u;
      const uint r01 = (uint)(st + iy1c * W + ix0c) * 256u;
      const uint r11 = (uint)(st + iy1c * W + ix1c) * 256u;
      const uint4 q00 = *(const uint4*)(value + base + r00);
      const uint4 q10 = *(const uint4*)(value + base + r10);
      const uint4 q01 = *(const uint4*)(value + base + r01);
      const uint4 q11 = *(const uint4*)(value + base + r11);
      const ushort* s00 = (const ushort*)&q00;
      const ushort* s10 = (const ushort*)&q10;
      const ushort* s01 = (const ushort*)&q01;
      const ushort* s11 = (const ushort*)&q11;
#pragma unroll
      for (int j = 0; j < 8; j++) {
        acc[j] += w00 * b2f(s00[j]) + w10 * b2f(s10[j]) +
                  w01 * b2f(s01[j]) + w11 * b2f(s11[j]);
      }
    }
  }
  ushort4 o0, o1;
  o0.x = f2b(acc[0]); o0.y = f2b(acc[1]); o0.z = f2b(acc[2]); o0.w = f2b(acc[3]);
  o1.x = f2b(acc[4]); o1.y = f2b(acc[5]); o1.z = f2b(acc[6]); o1.w = f2b(acc[7]);
  ushort* op = outb + (uint)tok * 256u + (uint)(l * 8);
  *(ushort4*)op = o0;
  *(ushort4*)(op + 4) = o1;
}

// ---------------- LayerNorm over 256 (wave per row, 4 rows/block) -----------
template <int OUTF>
__global__ __launch_bounds__(256) void ln256(
    const ushort* __restrict__ in, const float* __restrict__ gg,
    const float* __restrict__ bb, ushort* __restrict__ outb,
    float* __restrict__ outf, int rows)
{
  const int wave = threadIdx.x >> 6, lane = threadIdx.x & 63;
  const int r = blockIdx.x * 4 + wave;
  if (r >= rows) return;
  const ushort* rowp = in + (size_t)r * 256;
  const ushort4 u = *(const ushort4*)(rowp + lane * 4);
  float v[4] = {b2f(u.x), b2f(u.y), b2f(u.z), b2f(u.w)};
  float s = v[0] + v[1] + v[2] + v[3];
  float s2 = v[0] * v[0] + v[1] * v[1] + v[2] * v[2] + v[3] * v[3];
#pragma unroll
  for (int o = 32; o > 0; o >>= 1) {
    s += __shfl_xor(s, o);
    s2 += __shfl_xor(s2, o);
  }
  const float mean = s * (1.f / 256.f);
  const float var = s2 * (1.f / 256.f) - mean * mean;
  const float rstd = rsqrtf(var + 1e-5f);
#pragma unroll
  for (int j = 0; j < 4; j++) {
    const int col = lane * 4 + j;
    const float o = (v[j] - mean) * rstd * gg[col] + bb[col];
    if (OUTF) outf[(size_t)r * 256 + col] = o;
    else outb[(size_t)r * 256 + col] = f2b(o);
  }
}

// ---------------------------------------------------------------------------
extern "C" void kernel_launch(void* const* d_in, const int* in_sizes, int n_in,
                              void* d_out, int out_size, void* d_ws, size_t ws_size,
                              hipStream_t stream)
{
  const float* src   = (const float*)d_in[0];
  const float* pos   = (const float*)d_in[1];
  const float* refp  = (const float*)d_in[2];
  const float* Wv    = (const float*)d_in[3];
  const float* bv    = (const float*)d_in[4];
  const float* Woff  = (const float*)d_in[5];
  const float* boff  = (const float*)d_in[6];
  const float* Wattn = (const float*)d_in[7];
  const float* battn = (const float*)d_in[8];
  const float* Wout  = (const float*)d_in[9];
  const float* bout  = (const float*)d_in[10];
  const float* g1    = (const float*)d_in[11];
  const float* b1    = (const float*)d_in[12];
  const float* Wff1  = (const float*)d_in[13];
  const float* bff1  = (const float*)d_in[14];
  const float* Wff2  = (const float*)d_in[15];
  const float* bff2  = (const float*)d_in[16];
  const float* g2    = (const float*)d_in[17];
  const float* b2    = (const float*)d_in[18];
  float* out = (float*)d_out;
  char* ws = (char*)d_ws;

  // workspace (bytes). wv_t / wout_t overlaid on A5 tail: dead before G4
  // writes A5 (G1 consumes wv_t, G3 consumes wout_t, G4 runs after both).
  ushort* wcat_t = (ushort*)(ws + 0);            //   196608 (384 x 256)
  ushort* wff1_t = (ushort*)(ws + 196608);       //   524288
  ushort* wff2_t = (ushort*)(ws + 720896);       //   524288
  float*  bcat   = (float*)(ws + 1245184);       //     1536
  ushort* A1 = (ushort*)(ws + 1246720);          // src_bf -> attn_out (MP x 256)
  ushort* A2 = (ushort*)(ws + 28182016);         // q_bf   -> x_bf     (MP x 256)
  ushort* A3 = (ushort*)(ws + 55117312);         // value  -> y_bf     (BL x 256)
  ushort* A4 = (ushort*)(ws + 81997312);         // offattn(320) -> xpre(256)
  ushort* A5 = (ushort*)(ws + 115597312);        // h (MP x 1024)
  ushort* wout_t = (ushort*)(ws + 223076352);    //   131072 (inside A5 tail)
  ushort* wv_t   = (ushort*)(ws + 223207424);    //   131072 (inside A5 tail)
  // end: 223338496

  prep_weights<<<2946, 256, 0, stream>>>(Wv, Woff, Wattn, Wout, Wff1, Wff2,
                                         boff, battn,
                                         wv_t, wcat_t, wout_t, wff1_t, wff2_t, bcat);
  prep_act<<<MP / 4, 256, 0, stream>>>(src, pos, A1, A2);
  // G1: value = src @ Wv + bv
  gemm128<0><<<dim3(MP / 128, 2), 256, 0, stream>>>(A1, wv_t, bv, nullptr, nullptr,
                                                    A3, BLTOK, 256, 256, 256);
  // G2: offattn = q @ Wcat + bcat  (N=320, tiles to 384)
  gemm128<0><<<dim3(MP / 128, 3), 256, 0, stream>>>(A2, wcat_t, bcat, nullptr, nullptr,
                                                    A4, BLTOK, 320, 320, 256);
  softmax12<<<(BLTOK * 8 + 255) / 256, 256, 0, stream>>>(A4);
  deform_sample<<<(BLTOK + 7) / 8, 256, 0, stream>>>(A3, A4, refp, A1);
  // G3: xpre = src + attn_out @ Wout + bout
  gemm128<1><<<dim3(MP / 128, 2), 256, 0, stream>>>(A1, wout_t, bout, src, nullptr,
                                                    A4, BLTOK, 256, 256, 256);
  ln256<0><<<BLTOK / 4, 256, 0, stream>>>(A4, g1, b1, A2, nullptr, BLTOK);
  // G4: h = relu(x @ Wff1 + bff1)  — store pad rows too (A2 pads are zero)
  gemm128<2><<<dim3(MP / 128, 8), 256, 0, stream>>>(A2, wff1_t, bff1, nullptr, nullptr,
                                                    A5, MP, 1024, 1024, 256);
  // G5: y = x + h @ Wff2 + bff2
  gemm128<3><<<dim3(MP / 128, 2), 256, 0, stream>>>(A5, wff2_t, bff2, nullptr, A2,
                                                    A3, BLTOK, 256, 256, 1024);
  ln256<1><<<BLTOK / 4, 256, 0, stream>>>(A3, g2, b2, nullptr, out, BLTOK);
}

// Round 4
// 484.340 us; speedup vs baseline: 1.3107x; 1.3107x over previous
//
#include <hip/hip_runtime.h>

// ---------------------------------------------------------------------------
// DeformableTransformer encoder layer, MI355X (gfx950).
// R4: gemm128 w/ double-buffered global_load_lds, coalesced LDS epilogue,
// grid flipped (N fastest) for A-tile L2 reuse; bf16 residual for G3;
// deform_sample float2 packed FMA.
// ---------------------------------------------------------------------------

#define BLTOK 52500   // B*L tokens
#define MP    52608   // BLTOK padded to multiple of 128
#define LSP   13125   // L (spatial length per batch)

using short8  = __attribute__((ext_vector_type(8))) short;
using ushort8v= __attribute__((ext_vector_type(8))) unsigned short;
using f32x4   = __attribute__((ext_vector_type(4))) float;
using fl2     = __attribute__((ext_vector_type(2))) float;

__device__ __forceinline__ ushort f2b(float f) {
  union { float f; unsigned u; } x; x.f = f;
  unsigned r = (x.u + 0x7fffu + ((x.u >> 16) & 1u)) >> 16;
  return (ushort)r;
}
__device__ __forceinline__ float b2f(ushort h) {
  union { unsigned u; float f; } x; x.u = ((unsigned)h) << 16;
  return x.f;
}

#define GLDS16(gp, lp) __builtin_amdgcn_global_load_lds( \
    (const __attribute__((address_space(1))) void*)(gp), \
    (__attribute__((address_space(3))) void*)(lp), 16, 0, 0)

// ---------------- weight prep: transpose to N x K, convert bf16 -------------
__global__ __launch_bounds__(256) void prep_weights(
    const float* __restrict__ Wv, const float* __restrict__ Woff,
    const float* __restrict__ Wattn, const float* __restrict__ Wout,
    const float* __restrict__ Wff1, const float* __restrict__ Wff2,
    const float* __restrict__ boff, const float* __restrict__ battn,
    ushort* __restrict__ wv_t, ushort* __restrict__ wcat_t,
    ushort* __restrict__ wout_t, ushort* __restrict__ wff1_t,
    ushort* __restrict__ wff2_t, float* __restrict__ bcat)
{
  int i = blockIdx.x * 256 + threadIdx.x;
  if (i < 65536) {
    int n = i >> 8, k = i & 255;
    wv_t[i] = f2b(Wv[k * 256 + n]);
    return;
  }
  int j = i - 65536;
  if (j < 98304) {                       // 384 rows (320.. zero)
    int n = j >> 8, k = j & 255;
    float v = (n < 192) ? Woff[k * 192 + n]
            : (n < 288) ? Wattn[k * 96 + (n - 192)] : 0.f;
    wcat_t[j] = f2b(v);
    return;
  }
  j -= 98304;
  if (j < 65536) {
    int n = j >> 8, k = j & 255;
    wout_t[j] = f2b(Wout[k * 256 + n]);
    return;
  }
  j -= 65536;
  if (j < 262144) {
    int n = j >> 8, k = j & 255;
    wff1_t[j] = f2b(Wff1[k * 1024 + n]);
    return;
  }
  j -= 262144;
  if (j < 262144) {
    int n = j >> 10, k = j & 1023;
    wff2_t[j] = f2b(Wff2[k * 256 + n]);
    return;
  }
  j -= 262144;
  if (j < 384) bcat[j] = (j < 192) ? boff[j] : (j < 288) ? battn[j - 192] : 0.f;
}

// ---------------- activation prep: bf16 src and q=src+pos, zero pad rows ----
__global__ __launch_bounds__(256) void prep_act(
    const float* __restrict__ src, const float* __restrict__ pos,
    ushort* __restrict__ src_bf, ushort* __restrict__ q_bf)
{
  const size_t e = ((size_t)blockIdx.x * 256 + threadIdx.x) * 4;
  if (e >= (size_t)MP * 256) return;
  ushort4 sb, qb;
  if (e < (size_t)BLTOK * 256) {
    const float4 s = *(const float4*)(src + e);
    const float4 p = *(const float4*)(pos + e);
    sb.x = f2b(s.x); sb.y = f2b(s.y); sb.z = f2b(s.z); sb.w = f2b(s.w);
    qb.x = f2b(s.x + p.x); qb.y = f2b(s.y + p.y);
    qb.z = f2b(s.z + p.z); qb.w = f2b(s.w + p.w);
  } else {
    sb.x = sb.y = sb.z = sb.w = 0;
    qb.x = qb.y = qb.z = qb.w = 0;
  }
  *(ushort4*)(src_bf + e) = sb;
  *(ushort4*)(q_bf + e) = qb;
}

// ---------------- GEMM 128x128, dbuf GLDS staging, coalesced epilogue -------
// grid = (Ntiles, Mtiles): consecutive blocks share the A m-tile (L2 reuse).
// EPI: 0 = bias; 1 = + addf(f32); 2 = relu; 3 = + addb(bf16)
template <int EPI>
__global__ __launch_bounds__(256) void gemm128(
    const ushort* __restrict__ A, const ushort* __restrict__ Bt,
    const float* __restrict__ bias, const float* __restrict__ addf,
    const ushort* __restrict__ addb, ushort* __restrict__ C,
    int Mact, int Nact, int Nstr, int K)
{
  __shared__ __align__(16) ushort sm[16384];     // 32 KB
  ushort* As = sm;                               // [2][4096]
  ushort* Bs = sm + 8192;                        // [2][4096]
  float*  epf = (float*)sm;                      // epilogue: 64 x 128 f32
  const int tid = threadIdx.x;
  const int wave = tid >> 6, lane = tid & 63;
  const int n0 = blockIdx.x * 128, m0 = blockIdx.y * 128;
  const int srow = lane >> 2, skc = (lane & 3) * 8;
  const ushort* Ag = A + (size_t)(m0 + wave * 32 + srow) * K + skc;
  const ushort* Bg = Bt + (size_t)(n0 + wave * 32 + srow) * K + skc;
  const int quad = lane >> 4, l16 = lane & 15;
  const int wm = (wave & 1) * 64, wn = (wave >> 1) * 64;
  f32x4 acc[4][4] = {};

#define STAGE(buf, kk) { \
    ushort* la = As + (buf) * 4096 + wave * 1024; \
    ushort* lb = Bs + (buf) * 4096 + wave * 1024; \
    GLDS16(Ag + (kk), la); \
    GLDS16(Ag + (kk) + 16 * K, la + 512); \
    GLDS16(Bg + (kk), lb); \
    GLDS16(Bg + (kk) + 16 * K, lb + 512); }

  STAGE(0, 0);
  int cur = 0;
  for (int k0 = 0; k0 < K; k0 += 32) {
    __syncthreads();                      // drains staging of `cur`
    if (k0 + 32 < K) STAGE(cur ^ 1, k0 + 32);   // prefetch overlaps compute
    const ushort* Ab = As + cur * 4096;
    const ushort* Bb = Bs + cur * 4096;
    short8 af[4], bf[4];
#pragma unroll
    for (int i = 0; i < 4; i++)
      af[i] = *(const short8*)(&Ab[(wm + i * 16 + l16) * 32 + quad * 8]);
#pragma unroll
    for (int j = 0; j < 4; j++)
      bf[j] = *(const short8*)(&Bb[(wn + j * 16 + l16) * 32 + quad * 8]);
#pragma unroll
    for (int i = 0; i < 4; i++)
#pragma unroll
      for (int j = 0; j < 4; j++)
        acc[i][j] = __builtin_amdgcn_mfma_f32_16x16x32_bf16(af[i], bf[j],
                                                            acc[i][j], 0, 0, 0);
    cur ^= 1;
  }
#undef STAGE

  // coalesced epilogue: two 64-row rounds through f32 LDS
  for (int half = 0; half < 2; half++) {
    __syncthreads();
    if ((wave & 1) == half) {
      // C/D: col = l16, row = quad*4 + r  [m89/m91]
#pragma unroll
      for (int i = 0; i < 4; i++)
#pragma unroll
        for (int j = 0; j < 4; j++)
#pragma unroll
          for (int r = 0; r < 4; r++)
            epf[(i * 16 + quad * 4 + r) * 128 + wn + j * 16 + l16] = acc[i][j][r];
    }
    __syncthreads();
    const int gm0 = m0 + half * 64;
#pragma unroll
    for (int g = 0; g < 4; g++) {
      const int lrow = g * 16 + (tid >> 4);
      const int col0 = (tid & 15) * 8;
      const int grow = gm0 + lrow;
      const int gcol = n0 + col0;
      if (grow < Mact && gcol < Nact) {
        float v[8];
#pragma unroll
        for (int c = 0; c < 8; c++) v[c] = epf[lrow * 128 + col0 + c] + bias[gcol + c];
        const size_t idx = (size_t)grow * Nstr + gcol;
        if (EPI == 1) {
          const float4 a0 = *(const float4*)(addf + idx);
          const float4 a1 = *(const float4*)(addf + idx + 4);
          v[0] += a0.x; v[1] += a0.y; v[2] += a0.z; v[3] += a0.w;
          v[4] += a1.x; v[5] += a1.y; v[6] += a1.z; v[7] += a1.w;
        }
        if (EPI == 2) {
#pragma unroll
          for (int c = 0; c < 8; c++) v[c] = fmaxf(v[c], 0.f);
        }
        if (EPI == 3) {
          const ushort8v ab = *(const ushort8v*)(addb + idx);
#pragma unroll
          for (int c = 0; c < 8; c++) v[c] += b2f(ab[c]);
        }
        ushort8v o;
#pragma unroll
        for (int c = 0; c < 8; c++) o[c] = f2b(v[c]);
        *(ushort8v*)(C + idx) = o;
      }
    }
  }
}

// ---------------- softmax over 12 attn logits per (token, head), in place ---
__global__ __launch_bounds__(256) void softmax12(ushort* __restrict__ offattn)
{
  const int t = blockIdx.x * 256 + threadIdx.x;
  if (t >= BLTOK * 8) return;
  const int r = t >> 3, h = t & 7;
  ushort* p = offattn + (size_t)r * 320 + 192 + h * 12;
  float v[12], mx = -1e30f;
#pragma unroll
  for (int i = 0; i < 12; i++) { v[i] = b2f(p[i]); mx = fmaxf(mx, v[i]); }
  float s = 0.f;
#pragma unroll
  for (int i = 0; i < 12; i++) { v[i] = expf(v[i] - mx); s += v[i]; }
  const float inv = 1.f / s;
#pragma unroll
  for (int i = 0; i < 12; i++) p[i] = f2b(v[i] * inv);
}

// ---------------- MS-deform-attn bilinear sampling core ---------------------
// 32 lanes/token: lane l -> head h=l>>2, 8 channels. float2 packed FMAs.
__global__ __launch_bounds__(256) void deform_sample(
    const ushort* __restrict__ value, const ushort* __restrict__ oa_all,
    const float* __restrict__ refp, ushort* __restrict__ outb)
{
  const int tid = threadIdx.x;
  const int tok = blockIdx.x * 8 + (tid >> 5);
  if (tok >= BLTOK) return;
  const int b = tok / LSP;
  const int l = tid & 31;
  const int h = l >> 2;
  const ushort* oa = oa_all + (uint)tok * 320u;
  const float* rp = refp + (uint)tok * 6u;
  const uint base = (uint)b * (LSP * 256u) + (uint)(l * 8);
  const int Wl[3] = {100, 50, 25};
  const int Stl[3] = {0, 10000, 12500};
  fl2 acc2[4] = {};
#pragma unroll
  for (int lid = 0; lid < 3; lid++) {
    const int W = Wl[lid], st = Stl[lid];   // square levels: H == W
    const float Wf = (float)W;
    const float rx = rp[lid * 2], ry = rp[lid * 2 + 1];
#pragma unroll
    for (int p = 0; p < 4; p++) {
      const uint oxy = *(const uint*)(oa + h * 24 + lid * 8 + p * 2);
      union { uint u; float f; } ux, uy;
      ux.u = oxy << 16;
      uy.u = oxy & 0xffff0000u;
      const float aw = b2f(oa[192 + h * 12 + lid * 4 + p]);
      const float x = (rx + ux.f / Wf) * Wf - 0.5f;
      const float y = (ry + uy.f / Wf) * Wf - 0.5f;
      const float x0f = floorf(x), y0f = floorf(y);
      const float wx1 = x - x0f, wy1 = y - y0f;
      const float wx0 = 1.f - wx1, wy0 = 1.f - wy1;
      const int ix0 = (int)x0f, iy0 = (int)y0f;
      const bool x0v = (ix0 >= 0) & (ix0 < W);
      const bool x1v = (ix0 + 1 >= 0) & (ix0 + 1 < W);
      const bool y0v = (iy0 >= 0) & (iy0 < W);
      const bool y1v = (iy0 + 1 >= 0) & (iy0 + 1 < W);
      const float ay0 = aw * wy0, ay1 = aw * wy1;
      const float w00 = (x0v & y0v) ? ay0 * wx0 : 0.f;
      const float w10 = (x1v & y0v) ? ay0 * wx1 : 0.f;
      const float w01 = (x0v & y1v) ? ay1 * wx0 : 0.f;
      const float w11 = (x1v & y1v) ? ay1 * wx1 : 0.f;
      const int ix0c = min(max(ix0, 0), W - 1);
      const int ix1c = min(max(ix0 + 1, 0), W - 1);
      const int iy0c = min(max(iy0, 0), W - 1);
      const int iy1c = min(max(iy0 + 1, 0), W - 1);
      const uint r00 = (uint)(st + iy0c * W + ix0c) * 256u;
      const uint r10 = (uint)(st + iy0c * W + ix1c) * 256u;
      const uint r01 = (uint)(st + iy1c * W + ix0c) * 256u;
      const uint r11 = (uint)(st + iy1c * W + ix1c) * 256u;
      const uint4 q00 = *(const uint4*)(value + base + r00);
      const uint4 q10 = *(const uint4*)(value + base + r10);
      const uint4 q01 = *(const uint4*)(value + base + r01);
      const uint4 q11 = *(const uint4*)(value + base + r11);
      const fl2 w00v = {w00, w00}, w10v = {w10, w10};
      const fl2 w01v = {w01, w01}, w11v = {w11, w11};
      const uint* u00 = (const uint*)&q00;
      const uint* u10 = (const uint*)&q10;
      const uint* u01 = (const uint*)&q01;
      const uint* u11 = (const uint*)&q11;
#pragma unroll
      for (int pp = 0; pp < 4; pp++) {
        union { uint u; float f; } a, bb2, cc, dd, a2, b2u, c2, d2;
        a.u  = u00[pp] << 16;  a2.u  = u00[pp] & 0xffff0000u;
        bb2.u= u10[pp] << 16;  b2u.u = u10[pp] & 0xffff0000u;
        cc.u = u01[pp] << 16;  c2.u  = u01[pp] & 0xffff0000u;
        dd.u = u11[pp] << 16;  d2.u  = u11[pp] & 0xffff0000u;
        fl2 v00 = {a.f, a2.f}, v10 = {bb2.f, b2u.f};
        fl2 v01 = {cc.f, c2.f}, v11 = {dd.f, d2.f};
        acc2[pp] += w00v * v00 + w10v * v10 + w01v * v01 + w11v * v11;
      }
    }
  }
  ushort4 o0, o1;
  o0.x = f2b(acc2[0].x); o0.y = f2b(acc2[0].y);
  o0.z = f2b(acc2[1].x); o0.w = f2b(acc2[1].y);
  o1.x = f2b(acc2[2].x); o1.y = f2b(acc2[2].y);
  o1.z = f2b(acc2[3].x); o1.w = f2b(acc2[3].y);
  ushort* op = outb + (uint)tok * 256u + (uint)(l * 8);
  *(ushort4*)op = o0;
  *(ushort4*)(op + 4) = o1;
}

// ---------------- LayerNorm over 256 (wave per row, 4 rows/block) -----------
template <int OUTF>
__global__ __launch_bounds__(256) void ln256(
    const ushort* __restrict__ in, const float* __restrict__ gg,
    const float* __restrict__ bb, ushort* __restrict__ outb,
    float* __restrict__ outf, int rows)
{
  const int wave = threadIdx.x >> 6, lane = threadIdx.x & 63;
  const int r = blockIdx.x * 4 + wave;
  if (r >= rows) return;
  const ushort* rowp = in + (size_t)r * 256;
  const ushort4 u = *(const ushort4*)(rowp + lane * 4);
  float v[4] = {b2f(u.x), b2f(u.y), b2f(u.z), b2f(u.w)};
  float s = v[0] + v[1] + v[2] + v[3];
  float s2 = v[0] * v[0] + v[1] * v[1] + v[2] * v[2] + v[3] * v[3];
#pragma unroll
  for (int o = 32; o > 0; o >>= 1) {
    s += __shfl_xor(s, o);
    s2 += __shfl_xor(s2, o);
  }
  const float mean = s * (1.f / 256.f);
  const float var = s2 * (1.f / 256.f) - mean * mean;
  const float rstd = rsqrtf(var + 1e-5f);
#pragma unroll
  for (int j = 0; j < 4; j++) {
    const int col = lane * 4 + j;
    const float o = (v[j] - mean) * rstd * gg[col] + bb[col];
    if (OUTF) outf[(size_t)r * 256 + col] = o;
    else outb[(size_t)r * 256 + col] = f2b(o);
  }
}

// ---------------------------------------------------------------------------
extern "C" void kernel_launch(void* const* d_in, const int* in_sizes, int n_in,
                              void* d_out, int out_size, void* d_ws, size_t ws_size,
                              hipStream_t stream)
{
  const float* src   = (const float*)d_in[0];
  const float* pos   = (const float*)d_in[1];
  const float* refp  = (const float*)d_in[2];
  const float* Wv    = (const float*)d_in[3];
  const float* bv    = (const float*)d_in[4];
  const float* Woff  = (const float*)d_in[5];
  const float* boff  = (const float*)d_in[6];
  const float* Wattn = (const float*)d_in[7];
  const float* battn = (const float*)d_in[8];
  const float* Wout  = (const float*)d_in[9];
  const float* bout  = (const float*)d_in[10];
  const float* g1    = (const float*)d_in[11];
  const float* b1    = (const float*)d_in[12];
  const float* Wff1  = (const float*)d_in[13];
  const float* bff1  = (const float*)d_in[14];
  const float* Wff2  = (const float*)d_in[15];
  const float* bff2  = (const float*)d_in[16];
  const float* g2    = (const float*)d_in[17];
  const float* b2    = (const float*)d_in[18];
  float* out = (float*)d_out;
  char* ws = (char*)d_ws;

  // workspace (bytes). wv_t / wout_t overlaid on A5 tail (dead before G4
  // writes h there); attn_out uses A5's head (dead until G4).
  ushort* wcat_t = (ushort*)(ws + 0);            //   196608 (384 x 256)
  ushort* wff1_t = (ushort*)(ws + 196608);       //   524288
  ushort* wff2_t = (ushort*)(ws + 720896);       //   524288
  float*  bcat   = (float*)(ws + 1245184);       //     1536
  ushort* A1 = (ushort*)(ws + 1246720);          // src_bf (lives to G3)
  ushort* A2 = (ushort*)(ws + 28182016);         // q_bf -> x_bf
  ushort* A3 = (ushort*)(ws + 55117312);         // value -> y_bf
  ushort* A4 = (ushort*)(ws + 81997312);         // offattn(320) -> xpre(256)
  ushort* A5 = (ushort*)(ws + 115597312);        // attn_out (head) -> h (MPx1024)
  ushort* wout_t = (ushort*)(ws + 223076352);    //   131072 (A5 tail)
  ushort* wv_t   = (ushort*)(ws + 223207424);    //   131072 (A5 tail)
  // end: 223338496

  prep_weights<<<2946, 256, 0, stream>>>(Wv, Woff, Wattn, Wout, Wff1, Wff2,
                                         boff, battn,
                                         wv_t, wcat_t, wout_t, wff1_t, wff2_t, bcat);
  prep_act<<<MP / 4, 256, 0, stream>>>(src, pos, A1, A2);
  // G1: value = src @ Wv + bv
  gemm128<0><<<dim3(2, MP / 128), 256, 0, stream>>>(A1, wv_t, bv, nullptr, nullptr,
                                                    A3, BLTOK, 256, 256, 256);
  // G2: offattn = q @ Wcat + bcat  (N=320, tiles to 384)
  gemm128<0><<<dim3(3, MP / 128), 256, 0, stream>>>(A2, wcat_t, bcat, nullptr, nullptr,
                                                    A4, BLTOK, 320, 320, 256);
  softmax12<<<(BLTOK * 8 + 255) / 256, 256, 0, stream>>>(A4);
  // attn_out -> A5 head
  deform_sample<<<(BLTOK + 7) / 8, 256, 0, stream>>>(A3, A4, refp, A5);
  // G3: xpre = src_bf + attn_out @ Wout + bout  (bf16 residual from A1)
  gemm128<3><<<dim3(2, MP / 128), 256, 0, stream>>>(A5, wout_t, bout, nullptr, A1,
                                                    A4, BLTOK, 256, 256, 256);
  ln256<0><<<BLTOK / 4, 256, 0, stream>>>(A4, g1, b1, A2, nullptr, BLTOK);
  // G4: h = relu(x @ Wff1 + bff1) — store pad rows too (A2 pads are zero)
  gemm128<2><<<dim3(8, MP / 128), 256, 0, stream>>>(A2, wff1_t, bff1, nullptr, nullptr,
                                                    A5, MP, 1024, 1024, 256);
  // G5: y = x + h @ Wff2 + bff2
  gemm128<3><<<dim3(2, MP / 128), 256, 0, stream>>>(A5, wff2_t, bff2, nullptr, A2,
                                                    A3, BLTOK, 256, 256, 1024);
  ln256<1><<<BLTOK / 4, 256, 0, stream>>>(A3, g2, b2, nullptr, out, BLTOK);
}